// Round 2
// baseline (35.227 us; speedup 1.0000x reference)
//
#include <hip/hip_runtime.h>
#include <hip/hip_bf16.h>

#define NFIELDS 32
#define DDIM 64
#define NPAIR 496        // 32*31/2
#define BATCH_BYTES 8192 // 32*64*4

typedef __attribute__((ext_vector_type(8))) __bf16 bf16x8;
typedef __attribute__((ext_vector_type(4))) float f32x4;

__device__ __forceinline__ int pair_idx(int i, int j) {
    // pairs before row i = 31*i - i*(i-1)/2 ; then offset (j-i-1)
    return i * 31 - (i * (i - 1)) / 2 + (j - i - 1);
}

// Swizzle: XOR byte-bits [4:7] (16B-chunk index within a 256B row) with row&15.
// Involution; bits >=8 (row) unchanged, so it permutes chunks WITHIN a row only.
__device__ __forceinline__ int swz(int b) {
    return b ^ (((b >> 8) & 15) << 4);
}

__global__ __launch_bounds__(256) void inner_product_kernel(
        const float* __restrict__ x, float* __restrict__ out, int nbatch) {
    __shared__ __align__(16) char smem_raw[4][BATCH_BYTES];
    const int wib  = threadIdx.x >> 6;
    const int lane = threadIdx.x & 63;
    const int wave = blockIdx.x * 4 + wib;   // one wave per batch element
    if (wave >= nbatch) return;

    const char* xb  = (const char*)(x + (size_t)wave * (NFIELDS * DDIM));
    char*       lds = smem_raw[wib];

    // ---- dense global -> LDS staging (8 x 1KB, source pre-swizzled) ----
#pragma unroll
    for (int i = 0; i < 8; ++i) {
        const int b  = i * 1024 + lane * 16;
        const int sb = swz(b);
        __builtin_amdgcn_global_load_lds(
            (const __attribute__((address_space(1))) void*)(xb + sb),
            (__attribute__((address_space(3))) void*)(lds + i * 1024),
            16, 0, 0);
    }
    asm volatile("s_waitcnt vmcnt(0)" ::: "memory");

    // ---- LDS -> MFMA fragments (swizzled reads, ~2-way bank aliasing) ----
    const int r = lane & 15;   // row within 16-row tile
    const int g = lane >> 4;   // k-group (8 consecutive k)
    bf16x8 F[2][2];
#pragma unroll
    for (int rt = 0; rt < 2; ++rt) {
#pragma unroll
        for (int kt = 0; kt < 2; ++kt) {
            const int b0 = (rt * 16 + r) * 256 + kt * 128 + g * 32;
            const float4 a = *(const float4*)(lds + swz(b0));
            const float4 c = *(const float4*)(lds + swz(b0 + 16));
            bf16x8 f;
            f[0] = (__bf16)a.x; f[1] = (__bf16)a.y; f[2] = (__bf16)a.z; f[3] = (__bf16)a.w;
            f[4] = (__bf16)c.x; f[5] = (__bf16)c.y; f[6] = (__bf16)c.z; f[7] = (__bf16)c.w;
            F[rt][kt] = f;
        }
    }

    // ---- Gram tiles: A-frag == B-frag (C = X * X^T) ----
    f32x4 acc00 = {0.f, 0.f, 0.f, 0.f};
    f32x4 acc01 = {0.f, 0.f, 0.f, 0.f};
    f32x4 acc11 = {0.f, 0.f, 0.f, 0.f};
    acc00 = __builtin_amdgcn_mfma_f32_16x16x32_bf16(F[0][0], F[0][0], acc00, 0, 0, 0);
    acc00 = __builtin_amdgcn_mfma_f32_16x16x32_bf16(F[0][1], F[0][1], acc00, 0, 0, 0);
    acc01 = __builtin_amdgcn_mfma_f32_16x16x32_bf16(F[0][0], F[1][0], acc01, 0, 0, 0);
    acc01 = __builtin_amdgcn_mfma_f32_16x16x32_bf16(F[0][1], F[1][1], acc01, 0, 0, 0);
    acc11 = __builtin_amdgcn_mfma_f32_16x16x32_bf16(F[1][0], F[1][0], acc11, 0, 0, 0);
    acc11 = __builtin_amdgcn_mfma_f32_16x16x32_bf16(F[1][1], F[1][1], acc11, 0, 0, 0);

    // ---- triu scatter store (C/D layout: col=lane&15, row=(lane>>4)*4+reg) ----
    float* ob = out + (size_t)wave * NPAIR;
    const int col  = lane & 15;
    const int rowb = (lane >> 4) * 4;
#pragma unroll
    for (int v = 0; v < 4; ++v) {       // tile (0,0)
        int i = rowb + v, j = col;
        if (j > i) __builtin_nontemporal_store(acc00[v], &ob[pair_idx(i, j)]);
    }
#pragma unroll
    for (int v = 0; v < 4; ++v) {       // tile (0,1): all valid
        int i = rowb + v, j = 16 + col;
        __builtin_nontemporal_store(acc01[v], &ob[pair_idx(i, j)]);
    }
#pragma unroll
    for (int v = 0; v < 4; ++v) {       // tile (1,1)
        int i = 16 + rowb + v, j = 16 + col;
        if (j > i) __builtin_nontemporal_store(acc11[v], &ob[pair_idx(i, j)]);
    }
}

extern "C" void kernel_launch(void* const* d_in, const int* in_sizes, int n_in,
                              void* d_out, int out_size, void* d_ws, size_t ws_size,
                              hipStream_t stream) {
    const float* x = (const float*)d_in[0];
    float* out = (float*)d_out;
    const int nbatch = in_sizes[0] / (NFIELDS * DDIM);   // 16384
    const int nblocks = (nbatch + 3) / 4;                // 4 waves/block
    inner_product_kernel<<<nblocks, 256, 0, stream>>>(x, out, nbatch);
}

// Round 3
// 31.857 us; speedup vs baseline: 1.1058x; 1.1058x over previous
//
#include <hip/hip_runtime.h>
#include <hip/hip_bf16.h>

#define NFIELDS 32
#define DDIM 64
#define NPAIR 496   // 32*31/2

typedef __attribute__((ext_vector_type(8))) __bf16 bf16x8;
typedef __attribute__((ext_vector_type(4))) float f32x4;

__device__ __forceinline__ int pair_idx(int i, int j) {
    // pairs before row i = 31*i - i*(i-1)/2 ; then offset (j-i-1)
    return i * 31 - (i * (i - 1)) / 2 + (j - i - 1);
}

__global__ __launch_bounds__(256) void inner_product_kernel(
        const float* __restrict__ x, float* __restrict__ out, int nbatch) {
    const int gtid = blockIdx.x * blockDim.x + threadIdx.x;
    const int wave = gtid >> 6;        // one wave per batch element
    const int lane = threadIdx.x & 63;
    if (wave >= nbatch) return;

    const float* xb = x + (size_t)wave * (NFIELDS * DDIM);
    const int r = lane & 15;   // fragment row within 16-row tile (fixed by MFMA)
    const int g = lane >> 4;   // k-group 0..3

    // k-permuted fragment load: lane (r,g) takes floats {g*4..g*4+3} and
    // {16+g*4..16+g*4+3} of each 32-float k-block. Per load instruction the
    // four g-lanes of a row cover one FULL 64B line (100% segment utilization
    // vs 50% for the standard g*8 mapping). The permutation is a k-bijection
    // applied identically to the A and B operands (they are the same fragment
    // for C = X*X^T), so the Gram sum is unchanged.
    bf16x8 F[2][2];
#pragma unroll
    for (int rt = 0; rt < 2; ++rt) {
        const float* rowp = xb + (rt * 16 + r) * DDIM;
#pragma unroll
        for (int kt = 0; kt < 2; ++kt) {
            const float4 a = *reinterpret_cast<const float4*>(rowp + kt * 32 + g * 4);
            const float4 c = *reinterpret_cast<const float4*>(rowp + kt * 32 + 16 + g * 4);
            bf16x8 f;
            f[0] = (__bf16)a.x; f[1] = (__bf16)a.y; f[2] = (__bf16)a.z; f[3] = (__bf16)a.w;
            f[4] = (__bf16)c.x; f[5] = (__bf16)c.y; f[6] = (__bf16)c.z; f[7] = (__bf16)c.w;
            F[rt][kt] = f;
        }
    }

    f32x4 acc00 = {0.f, 0.f, 0.f, 0.f};
    f32x4 acc01 = {0.f, 0.f, 0.f, 0.f};
    f32x4 acc11 = {0.f, 0.f, 0.f, 0.f};
    acc00 = __builtin_amdgcn_mfma_f32_16x16x32_bf16(F[0][0], F[0][0], acc00, 0, 0, 0);
    acc00 = __builtin_amdgcn_mfma_f32_16x16x32_bf16(F[0][1], F[0][1], acc00, 0, 0, 0);
    acc01 = __builtin_amdgcn_mfma_f32_16x16x32_bf16(F[0][0], F[1][0], acc01, 0, 0, 0);
    acc01 = __builtin_amdgcn_mfma_f32_16x16x32_bf16(F[0][1], F[1][1], acc01, 0, 0, 0);
    acc11 = __builtin_amdgcn_mfma_f32_16x16x32_bf16(F[1][0], F[1][0], acc11, 0, 0, 0);
    acc11 = __builtin_amdgcn_mfma_f32_16x16x32_bf16(F[1][1], F[1][1], acc11, 0, 0, 0);

    // C/D layout (m89-verified): col = lane&15, row = (lane>>4)*4 + reg
    float* ob = out + (size_t)wave * NPAIR;
    const int col  = lane & 15;
    const int rowb = (lane >> 4) * 4;
#pragma unroll
    for (int v = 0; v < 4; ++v) {       // tile (0,0): i,j in [0,16)
        int i = rowb + v, j = col;
        if (j > i) ob[pair_idx(i, j)] = acc00[v];
    }
#pragma unroll
    for (int v = 0; v < 4; ++v) {       // tile (0,1): all valid
        int i = rowb + v, j = 16 + col;
        ob[pair_idx(i, j)] = acc01[v];
    }
#pragma unroll
    for (int v = 0; v < 4; ++v) {       // tile (1,1): i,j in [16,32)
        int i = 16 + rowb + v, j = 16 + col;
        if (j > i) ob[pair_idx(i, j)] = acc11[v];
    }
}

extern "C" void kernel_launch(void* const* d_in, const int* in_sizes, int n_in,
                              void* d_out, int out_size, void* d_ws, size_t ws_size,
                              hipStream_t stream) {
    const float* x = (const float*)d_in[0];
    float* out = (float*)d_out;
    const int nbatch = in_sizes[0] / (NFIELDS * DDIM);   // 16384
    const int nblocks = (nbatch + 3) / 4;                // 4 waves/block
    inner_product_kernel<<<nblocks, 256, 0, stream>>>(x, out, nbatch);
}

// Round 4
// 30.163 us; speedup vs baseline: 1.1679x; 1.0562x over previous
//
#include <hip/hip_runtime.h>
#include <hip/hip_bf16.h>

#define NFIELDS 32
#define DDIM 64
#define NPAIR 496   // 32*31/2

typedef __attribute__((ext_vector_type(8))) __bf16 bf16x8;
typedef __attribute__((ext_vector_type(4))) float f32x4;

__device__ __forceinline__ int pair_idx(int i, int j) {
    // pairs before row i = 31*i - i*(i-1)/2 ; then offset (j-i-1)
    return i * 31 - (i * (i - 1)) / 2 + (j - i - 1);
}

__global__ __launch_bounds__(256) void inner_product_kernel(
        const float* __restrict__ x, float* __restrict__ out, int nbatch) {
    // per-wave 2KB output staging buffer (512 floats; 496 used)
    __shared__ __align__(16) float obuf[4][512];
    const int wib  = threadIdx.x >> 6;
    const int lane = threadIdx.x & 63;
    const int wave = blockIdx.x * 4 + wib;   // one wave per batch element
    if (wave >= nbatch) return;

    const float* xb = x + (size_t)wave * (NFIELDS * DDIM);
    const int r = lane & 15;   // fragment row within 16-row tile
    const int g = lane >> 4;   // k-group 0..3

    // Dense coalesced fragment load (k-permuted; permutation applied to both
    // MFMA operands identically — they're the same fragment — so Gram unchanged).
    bf16x8 F[2][2];
#pragma unroll
    for (int rt = 0; rt < 2; ++rt) {
        const float* rowp = xb + (rt * 16 + r) * DDIM;
#pragma unroll
        for (int kt = 0; kt < 2; ++kt) {
            const float4 a = *reinterpret_cast<const float4*>(rowp + kt * 32 + g * 4);
            const float4 c = *reinterpret_cast<const float4*>(rowp + kt * 32 + 16 + g * 4);
            bf16x8 f;
            f[0] = (__bf16)a.x; f[1] = (__bf16)a.y; f[2] = (__bf16)a.z; f[3] = (__bf16)a.w;
            f[4] = (__bf16)c.x; f[5] = (__bf16)c.y; f[6] = (__bf16)c.z; f[7] = (__bf16)c.w;
            F[rt][kt] = f;
        }
    }

    f32x4 acc00 = {0.f, 0.f, 0.f, 0.f};
    f32x4 acc01 = {0.f, 0.f, 0.f, 0.f};
    f32x4 acc11 = {0.f, 0.f, 0.f, 0.f};
    acc00 = __builtin_amdgcn_mfma_f32_16x16x32_bf16(F[0][0], F[0][0], acc00, 0, 0, 0);
    acc00 = __builtin_amdgcn_mfma_f32_16x16x32_bf16(F[0][1], F[0][1], acc00, 0, 0, 0);
    acc01 = __builtin_amdgcn_mfma_f32_16x16x32_bf16(F[0][0], F[1][0], acc01, 0, 0, 0);
    acc01 = __builtin_amdgcn_mfma_f32_16x16x32_bf16(F[0][1], F[1][1], acc01, 0, 0, 0);
    acc11 = __builtin_amdgcn_mfma_f32_16x16x32_bf16(F[1][0], F[1][0], acc11, 0, 0, 0);
    acc11 = __builtin_amdgcn_mfma_f32_16x16x32_bf16(F[1][1], F[1][1], acc11, 0, 0, 0);

    // ---- scatter into per-wave LDS (wave-synchronous, no __syncthreads) ----
    float* ow = obuf[wib];
    const int col  = lane & 15;
    const int rowb = (lane >> 4) * 4;
#pragma unroll
    for (int v = 0; v < 4; ++v) {       // tile (0,0): i,j in [0,16)
        int i = rowb + v, j = col;
        if (j > i) ow[pair_idx(i, j)] = acc00[v];
    }
#pragma unroll
    for (int v = 0; v < 4; ++v) {       // tile (0,1): all valid
        int i = rowb + v, j = 16 + col;
        ow[pair_idx(i, j)] = acc01[v];
    }
#pragma unroll
    for (int v = 0; v < 4; ++v) {       // tile (1,1): i,j in [16,32)
        int i = 16 + rowb + v, j = 16 + col;
        if (j > i) ow[pair_idx(i, j)] = acc11[v];
    }
    // DS ops of a wave complete in order; drain before cross-lane read-back.
    asm volatile("s_waitcnt lgkmcnt(0)" ::: "memory");
    __builtin_amdgcn_sched_barrier(0);

    // ---- dense contiguous write-out: 1984B per wave, 16B-aligned ----
    char* ob = (char*)(out + (size_t)wave * NPAIR);
    const char* sb = (const char*)ow;
    float4 v0 = *reinterpret_cast<const float4*>(sb + lane * 16);
    *reinterpret_cast<float4*>(ob + lane * 16) = v0;           // bytes [0,1024)
    if (lane < 60) {                                           // bytes [1024,1984)
        float4 v1 = *reinterpret_cast<const float4*>(sb + 1024 + lane * 16);
        *reinterpret_cast<float4*>(ob + 1024 + lane * 16) = v1;
    }
}

extern "C" void kernel_launch(void* const* d_in, const int* in_sizes, int n_in,
                              void* d_out, int out_size, void* d_ws, size_t ws_size,
                              hipStream_t stream) {
    const float* x = (const float*)d_in[0];
    float* out = (float*)d_out;
    const int nbatch = in_sizes[0] / (NFIELDS * DDIM);   // 16384
    const int nblocks = (nbatch + 3) / 4;                // 4 waves/block
    inner_product_kernel<<<nblocks, 256, 0, stream>>>(x, out, nbatch);
}

// Round 5
// 30.116 us; speedup vs baseline: 1.1697x; 1.0016x over previous
//
#include <hip/hip_runtime.h>
#include <hip/hip_bf16.h>

#define NFIELDS 32
#define DDIM 64
#define NPAIR 496   // 32*31/2

typedef __attribute__((ext_vector_type(8))) __bf16 bf16x8;
typedef __attribute__((ext_vector_type(4))) float f32x4;

__device__ __forceinline__ int pair_idx(int i, int j) {
    // pairs before row i = 31*i - i*(i-1)/2 ; then offset (j-i-1)
    return i * 31 - (i * (i - 1)) / 2 + (j - i - 1);
}

__global__ __launch_bounds__(256) void inner_product_kernel(
        const float* __restrict__ x, float* __restrict__ out, int nbatch) {
    // per-wave staging for TWO batches' outputs, contiguous: [0,496) and [496,992)
    __shared__ __align__(16) float obuf[4][1024];
    const int wib  = threadIdx.x >> 6;
    const int lane = threadIdx.x & 63;
    const int wv   = blockIdx.x * 4 + wib;
    const int b0   = wv * 2;                 // two batches per wave
    if (b0 >= nbatch) return;

    const int r = lane & 15;
    const int g = lane >> 4;

    // ---- issue ALL 16 dense loads up front (2 batches x 8 x 1KB) ----
    // k-permuted fragment mapping (g*4 / 16+g*4): 100% line utilization per
    // instruction; permutation identical on both MFMA operands -> Gram unchanged.
    float4 raw[2][2][2][2];   // [batch][rt][kt][half]
#pragma unroll
    for (int b = 0; b < 2; ++b) {
        const float* xb = x + (size_t)(b0 + b) * (NFIELDS * DDIM);
#pragma unroll
        for (int rt = 0; rt < 2; ++rt) {
            const float* rowp = xb + (rt * 16 + r) * DDIM;
#pragma unroll
            for (int kt = 0; kt < 2; ++kt) {
                raw[b][rt][kt][0] = *reinterpret_cast<const float4*>(rowp + kt * 32 + g * 4);
                raw[b][rt][kt][1] = *reinterpret_cast<const float4*>(rowp + kt * 32 + 16 + g * 4);
            }
        }
    }

    // ---- per batch: convert -> 6 MFMA -> scatter into LDS ----
    float* owb = obuf[wib];
#pragma unroll
    for (int b = 0; b < 2; ++b) {
        bf16x8 F[2][2];
#pragma unroll
        for (int rt = 0; rt < 2; ++rt)
#pragma unroll
            for (int kt = 0; kt < 2; ++kt) {
                const float4 a = raw[b][rt][kt][0];
                const float4 c = raw[b][rt][kt][1];
                bf16x8 f;
                f[0] = (__bf16)a.x; f[1] = (__bf16)a.y; f[2] = (__bf16)a.z; f[3] = (__bf16)a.w;
                f[4] = (__bf16)c.x; f[5] = (__bf16)c.y; f[6] = (__bf16)c.z; f[7] = (__bf16)c.w;
                F[rt][kt] = f;
            }

        f32x4 acc00 = {0.f, 0.f, 0.f, 0.f};
        f32x4 acc01 = {0.f, 0.f, 0.f, 0.f};
        f32x4 acc11 = {0.f, 0.f, 0.f, 0.f};
        acc00 = __builtin_amdgcn_mfma_f32_16x16x32_bf16(F[0][0], F[0][0], acc00, 0, 0, 0);
        acc00 = __builtin_amdgcn_mfma_f32_16x16x32_bf16(F[0][1], F[0][1], acc00, 0, 0, 0);
        acc01 = __builtin_amdgcn_mfma_f32_16x16x32_bf16(F[0][0], F[1][0], acc01, 0, 0, 0);
        acc01 = __builtin_amdgcn_mfma_f32_16x16x32_bf16(F[0][1], F[1][1], acc01, 0, 0, 0);
        acc11 = __builtin_amdgcn_mfma_f32_16x16x32_bf16(F[1][0], F[1][0], acc11, 0, 0, 0);
        acc11 = __builtin_amdgcn_mfma_f32_16x16x32_bf16(F[1][1], F[1][1], acc11, 0, 0, 0);

        // C/D layout: col = lane&15, row = (lane>>4)*4 + reg
        float* ow = owb + b * NPAIR;
        const int col  = lane & 15;
        const int rowb = (lane >> 4) * 4;
#pragma unroll
        for (int v = 0; v < 4; ++v) {       // tile (0,0)
            int i = rowb + v, j = col;
            if (j > i) ow[pair_idx(i, j)] = acc00[v];
        }
#pragma unroll
        for (int v = 0; v < 4; ++v) {       // tile (0,1): all valid
            int i = rowb + v, j = 16 + col;
            ow[pair_idx(i, j)] = acc01[v];
        }
#pragma unroll
        for (int v = 0; v < 4; ++v) {       // tile (1,1)
            int i = 16 + rowb + v, j = 16 + col;
            if (j > i) ow[pair_idx(i, j)] = acc11[v];
        }
    }

    // wave-synchronous DS drain before cross-lane read-back
    asm volatile("s_waitcnt lgkmcnt(0)" ::: "memory");
    __builtin_amdgcn_sched_barrier(0);

    // ---- dense contiguous write-out: 992 floats = 3968B, 16B-aligned ----
    char* ob = (char*)(out + (size_t)b0 * NPAIR);
    const char* sb = (const char*)owb;
#pragma unroll
    for (int i = 0; i < 4; ++i) {
        const int q = i * 64 + lane;        // 248 quads total = 3*64 + 56
        if (q < 248) {
            float4 v = *reinterpret_cast<const float4*>(sb + q * 16);
            *reinterpret_cast<float4*>(ob + q * 16) = v;
        }
    }
}

extern "C" void kernel_launch(void* const* d_in, const int* in_sizes, int n_in,
                              void* d_out, int out_size, void* d_ws, size_t ws_size,
                              hipStream_t stream) {
    const float* x = (const float*)d_in[0];
    float* out = (float*)d_out;
    const int nbatch = in_sizes[0] / (NFIELDS * DDIM);   // 16384
    const int nwaves = (nbatch + 1) / 2;                 // 2 batches per wave
    const int nblocks = (nwaves + 3) / 4;                // 4 waves per block
    inner_product_kernel<<<nblocks, 256, 0, stream>>>(x, out, nbatch);
}